// Round 1
// baseline (59.715 us; speedup 1.0000x reference)
//
#include <hip/hip_runtime.h>

// out(p) = (48 - (g(p)·G(p) - g(p)·g(p))) / 8
//   g = x / max(||x||_2 over C, 1e-8)   (per pixel, C=3)
//   G = 7x7 zero-padded box-sum of g    (separable 7-tap H then V)
// Matches reference exactly: padded neighbors give dot=0, nn=eps -> term=1,
// i.e. contribute 0 to the windowed sum, which zero-padding g reproduces.

#define KWIN 7
#define MID 3
#define EPSV 1e-8f

constexpr int OUT_W = 64;
constexpr int OUT_H = 16;
constexpr int IN_W = OUT_W + (KWIN - 1);  // 70
constexpr int IN_H = OUT_H + (KWIN - 1);  // 22
constexpr int GP = IN_W + 1;              // 71: padded LDS stride
constexpr int HP = OUT_W + 1;             // 65: padded LDS stride

__global__ __launch_bounds__(256) void mcnd_kernel(const float* __restrict__ x,
                                                   float* __restrict__ out,
                                                   int B, int H, int W) {
    __shared__ float gs[3][IN_H][GP];   // normalized vectors (+halo)
    __shared__ float hs[3][IN_H][HP];   // horizontal 7-tap sums

    const int HW = H * W;
    const int tilesX = W / OUT_W;             // 8
    const int tilesY = H / OUT_H;             // 32
    const int tilesPerImg = tilesX * tilesY;  // 256

    const int bid = blockIdx.x;
    const int b  = bid / tilesPerImg;
    const int t  = bid % tilesPerImg;
    const int ty = t / tilesX;
    const int tx = t % tilesX;
    const int y0 = ty * OUT_H;
    const int x0 = tx * OUT_W;

    const float* __restrict__ xb = x + (size_t)b * 3 * HW;
    const int tid = threadIdx.x;

    // ---- stage 1: load halo tile, normalize per pixel, store g to LDS ----
    for (int p = tid; p < IN_H * IN_W; p += 256) {
        const int ly = p / IN_W;
        const int lx = p - ly * IN_W;
        const int gy = y0 + ly - MID;
        const int gx = x0 + lx - MID;
        float v0 = 0.0f, v1 = 0.0f, v2 = 0.0f;
        if (gy >= 0 && gy < H && gx >= 0 && gx < W) {
            const size_t idx = (size_t)gy * W + gx;
            v0 = xb[idx];
            v1 = xb[(size_t)HW + idx];
            v2 = xb[2 * (size_t)HW + idx];
            const float n   = sqrtf(v0 * v0 + v1 * v1 + v2 * v2);
            const float inv = 1.0f / fmaxf(n, EPSV);
            v0 *= inv; v1 *= inv; v2 *= inv;
        }
        gs[0][ly][lx] = v0;
        gs[1][ly][lx] = v1;
        gs[2][ly][lx] = v2;
    }
    __syncthreads();

    // ---- stage 2: horizontal 7-tap box sum ----
    for (int p = tid; p < IN_H * OUT_W; p += 256) {
        const int ly = p / OUT_W;
        const int lx = p - ly * OUT_W;
        float s0 = 0.0f, s1 = 0.0f, s2 = 0.0f;
#pragma unroll
        for (int d = 0; d < KWIN; ++d) {
            s0 += gs[0][ly][lx + d];
            s1 += gs[1][ly][lx + d];
            s2 += gs[2][ly][lx + d];
        }
        hs[0][ly][lx] = s0;
        hs[1][ly][lx] = s1;
        hs[2][ly][lx] = s2;
    }
    __syncthreads();

    // ---- stage 3: vertical 7-tap + dot + epilogue ----
    float* __restrict__ ob = out + (size_t)b * HW;
    for (int p = tid; p < OUT_H * OUT_W; p += 256) {
        const int ly = p / OUT_W;
        const int lx = p - ly * OUT_W;
        float G0 = 0.0f, G1 = 0.0f, G2 = 0.0f;
#pragma unroll
        for (int d = 0; d < KWIN; ++d) {
            G0 += hs[0][ly + d][lx];
            G1 += hs[1][ly + d][lx];
            G2 += hs[2][ly + d][lx];
        }
        const float g0 = gs[0][ly + MID][lx + MID];
        const float g1 = gs[1][ly + MID][lx + MID];
        const float g2 = gs[2][ly + MID][lx + MID];
        const float S  = g0 * G0 + g1 * G1 + g2 * G2
                       - (g0 * g0 + g1 * g1 + g2 * g2);
        ob[(size_t)(y0 + ly) * W + (x0 + lx)] = (48.0f - S) * 0.125f;
    }
}

extern "C" void kernel_launch(void* const* d_in, const int* in_sizes, int n_in,
                              void* d_out, int out_size, void* d_ws, size_t ws_size,
                              hipStream_t stream) {
    (void)n_in; (void)d_ws; (void)ws_size; (void)out_size;
    const float* x = (const float*)d_in[0];
    float* out = (float*)d_out;

    const int H = 512, W = 512, C = 3;
    const int B = in_sizes[0] / (C * H * W);  // 32

    const int tilesPerImg = (W / OUT_W) * (H / OUT_H);  // 256
    const int grid = B * tilesPerImg;                   // 8192
    mcnd_kernel<<<grid, 256, 0, stream>>>(x, out, B, H, W);
}

// Round 2
// 41.012 us; speedup vs baseline: 1.4560x; 1.4560x over previous
//
#include <hip/hip_runtime.h>

// out(p) = (48 - (g(p)·G(p) - g(p)·g(p))) / 8
//   g = x / max(||x||_2 over C, 1e-8)  (per pixel, C=3)
//   G = 7x7 zero-padded box-sum of g   (separable: 7-tap H into hs, then 7-tap V)
// Fully float4-vectorized: all LDS ops are aligned b128.

typedef float f32x4 __attribute__((ext_vector_type(4)));

#define EPS2 1e-16f   // max(sqrt(n2),1e-8) == sqrt(max(n2,1e-16))

constexpr int OUT_W = 64;
constexpr int OUT_H = 16;
constexpr int IN_H  = OUT_H + 6;   // 22 rows incl vertical halo
constexpr int GSTR  = 72;          // gs row stride; cols = image x0-4 .. x0+67 (18 float4)
constexpr int HSTR  = 68;          // hs row stride (68%32=4 -> rows staggered across banks)

__global__ __launch_bounds__(256) void mcnd_kernel(const float* __restrict__ x,
                                                   float* __restrict__ out,
                                                   int B, int H, int W) {
    __shared__ float gs[3][IN_H][GSTR];  // normalized g (+halo), 19.0 KB
    __shared__ float hs[3][IN_H][HSTR];  // horizontal 7-tap sums, 18.0 KB

    const int HW = H * W;
    const int tilesX = W / OUT_W;                 // 8
    const int tilesPerImg = tilesX * (H / OUT_H); // 256

    const int b  = blockIdx.x / tilesPerImg;
    const int t  = blockIdx.x % tilesPerImg;
    const int ty = t / tilesX;
    const int tx = t % tilesX;
    const int y0 = ty * OUT_H;
    const int x0 = tx * OUT_W;

    const float* __restrict__ xb = x + (size_t)b * 3 * HW;
    const int tid = threadIdx.x;

    // ---- stage 1: float4 load + normalize -> gs (halo chunks are wholly in/out) ----
    for (int p = tid; p < IN_H * 18; p += 256) {
        const int ly = p / 18;
        const int k  = p - ly * 18;
        const int gy = y0 + ly - 3;
        const int gx = x0 + k * 4 - 4;          // 16B-aligned image col base
        f32x4 a = {0.f, 0.f, 0.f, 0.f}, c1 = a, c2 = a;
        if (gy >= 0 && gy < H && gx >= 0 && gx < W) {
            const float* base = xb + (size_t)gy * W + gx;
            a  = *(const f32x4*)(base);
            c1 = *(const f32x4*)(base + HW);
            c2 = *(const f32x4*)(base + 2 * HW);
        }
        f32x4 g0, g1, g2;
#pragma unroll
        for (int e = 0; e < 4; ++e) {
            const float n2  = a[e] * a[e] + c1[e] * c1[e] + c2[e] * c2[e];
            const float inv = __builtin_amdgcn_rsqf(fmaxf(n2, EPS2));
            g0[e] = a[e] * inv; g1[e] = c1[e] * inv; g2[e] = c2[e] * inv;
        }
        const int cc = k * 4;
        *(f32x4*)&gs[0][ly][cc] = g0;
        *(f32x4*)&gs[1][ly][cc] = g1;
        *(f32x4*)&gs[2][ly][cc] = g2;
    }
    __syncthreads();

    // ---- stage 2: horizontal 7-tap via 3 aligned b128 reads + sliding adds ----
    for (int p = tid; p < IN_H * 16; p += 256) {
        const int ly = p >> 4;
        const int cc = (p & 15) * 4;            // output col group (image x0+cc..+3)
#pragma unroll
        for (int ch = 0; ch < 3; ++ch) {
            const float* row = gs[ch][ly];
            const f32x4 v0 = *(const f32x4*)(row + cc);
            const f32x4 v1 = *(const f32x4*)(row + cc + 4);
            const f32x4 v2 = *(const f32x4*)(row + cc + 8);
            // window for out col cc+e: LDS cols cc+e+1 .. cc+e+7
            const float h0 = v0[1] + v0[2] + v0[3] + v1[0] + v1[1] + v1[2] + v1[3];
            const float h1 = h0 - v0[1] + v2[0];
            const float h2 = h1 - v0[2] + v2[1];
            const float h3 = h2 - v0[3] + v2[2];
            const f32x4 hv = {h0, h1, h2, h3};
            *(f32x4*)&hs[ch][ly][cc] = hv;
        }
    }
    __syncthreads();

    // ---- stage 3: vertical 7-tap (b128) + dot + store ----
    {
        const int ry = tid >> 4;                // 0..15
        const int cc = (tid & 15) * 4;
        f32x4 G0 = {0.f, 0.f, 0.f, 0.f}, G1 = G0, G2 = G0;
#pragma unroll
        for (int d = 0; d < 7; ++d) {
            G0 += *(const f32x4*)&hs[0][ry + d][cc];
            G1 += *(const f32x4*)&hs[1][ry + d][cc];
            G2 += *(const f32x4*)&hs[2][ry + d][cc];
        }
        // center g: LDS col cc+4+e == image col x0+cc+e (aligned b128)
        const f32x4 c0 = *(const f32x4*)&gs[0][ry + 3][cc + 4];
        const f32x4 c1 = *(const f32x4*)&gs[1][ry + 3][cc + 4];
        const f32x4 c2 = *(const f32x4*)&gs[2][ry + 3][cc + 4];
        f32x4 r;
#pragma unroll
        for (int e = 0; e < 4; ++e) {
            const float S = c0[e] * G0[e] + c1[e] * G1[e] + c2[e] * G2[e]
                          - (c0[e] * c0[e] + c1[e] * c1[e] + c2[e] * c2[e]);
            r[e] = (48.0f - S) * 0.125f;
        }
        float* __restrict__ ob = out + (size_t)b * HW;
        *(f32x4*)(ob + (size_t)(y0 + ry) * W + (x0 + cc)) = r;
    }
}

extern "C" void kernel_launch(void* const* d_in, const int* in_sizes, int n_in,
                              void* d_out, int out_size, void* d_ws, size_t ws_size,
                              hipStream_t stream) {
    (void)n_in; (void)d_ws; (void)ws_size; (void)out_size;
    const float* x = (const float*)d_in[0];
    float* out = (float*)d_out;

    const int H = 512, W = 512, C = 3;
    const int B = in_sizes[0] / (C * H * W);            // 32

    const int tilesPerImg = (W / OUT_W) * (H / OUT_H);  // 256
    mcnd_kernel<<<B * tilesPerImg, 256, 0, stream>>>(x, out, B, H, W);
}